// Round 3
// baseline (16.543 us; speedup 1.0000x reference)
//
#include <hip/hip_runtime.h>

// KAN activation: out[b,o,i] = sum_t B_t(x[b,i]) * coef[o,i,t]
// B=2048, IN=OUT=64, uniform knots (15), order k=3, 11 basis funcs.
//
// Uniform grid -> closed-form cubic B-spline: only 4 consecutive bases are
// nonzero, weights are cubic polynomials of the fractional cell position.
//
// Phase 1: 1 (b,i) pair per thread; analytic weights scattered into a dense
//          12-slot row stored as 3 float4 planes in LDS (conflict-free b128).
// Phase 2: thread owns (i, 4 consecutive o); 44 coef in registers; 3x
//          ds_read_b128 per batch row shared across 4 outputs; NT stores.
//
// B_TILE=4 -> 2048 blocks = 8 blocks/CU (32 waves/CU), 12 KiB LDS.

#define BATCH    2048
#define IN_DIM   64
#define OUT_DIM  64
#define NCOEF    11     // G + k
#define B_TILE   4
#define O_TILE   16     // per block (4 groups x 4 o each)
#define NPAIR    (B_TILE * IN_DIM)        // 256
#define PLANE    (NPAIR * 4)              // floats per plane

__global__ __launch_bounds__(256) void kan_kernel(
    const float* __restrict__ x,     // (2048, 64)
    const float* __restrict__ grid,  // (64, 64, 15) broadcast uniform knots
    const float* __restrict__ coef,  // (64, 64, 11)
    float* __restrict__ out)         // (2048, 64, 64)
{
    __shared__ float lds[3 * PLANE];  // 12 KiB

    const int tid    = threadIdx.x;
    const int o_tile = blockIdx.x & 3;        // 4 o-tiles of 16
    const int b_tile = blockIdx.x >> 2;       // 512 b-tiles of 4
    const int b0     = b_tile * B_TILE;

    const float g0    = grid[0];
    const float inv_h = 1.0f / (grid[1] - g0);   // one divide per thread

    // ---- Phase 1: analytic cubic B-spline weights, 1 pair per thread ----
    {
        const int p  = tid;                  // p = bb*64 + i
        const int bb = p >> 6;
        const int i  = p & 63;
        const float xv = x[(size_t)(b0 + bb) * IN_DIM + i];  // issue early

        const float4 z = make_float4(0.f, 0.f, 0.f, 0.f);
        *(float4*)&lds[0 * PLANE + p * 4] = z;
        *(float4*)&lds[1 * PLANE + p * 4] = z;
        *(float4*)&lds[2 * PLANE + p * 4] = z;

        const float pos = (xv - g0) * inv_h;   // cell position in [0,14)
        if (pos >= 0.0f && pos < 14.0f) {
            const int   m  = (int)pos;
            const float t  = pos - (float)m;
            const float t2 = t * t;
            const float t3 = t2 * t;
            const float s  = 1.0f - t;
            const float w0 = s * s * s * (1.0f / 6.0f);
            const float w1 = (3.0f * t3 - 6.0f * t2 + 4.0f) * (1.0f / 6.0f);
            const float w2 = (-3.0f * t3 + 3.0f * t2 + 3.0f * t + 1.0f) * (1.0f / 6.0f);
            const float w3 = t3 * (1.0f / 6.0f);

            const int mb = m - 3;              // dense index of w0
            int idx;
            idx = mb + 0; if ((unsigned)idx < NCOEF) lds[(idx >> 2) * PLANE + p * 4 + (idx & 3)] = w0;
            idx = mb + 1; if ((unsigned)idx < NCOEF) lds[(idx >> 2) * PLANE + p * 4 + (idx & 3)] = w1;
            idx = mb + 2; if ((unsigned)idx < NCOEF) lds[(idx >> 2) * PLANE + p * 4 + (idx & 3)] = w2;
            idx = mb + 3; if ((unsigned)idx < NCOEF) lds[(idx >> 2) * PLANE + p * 4 + (idx & 3)] = w3;
        }
    }
    __syncthreads();

    // ---- Phase 2: thread owns (i, 4 consecutive o); coef in registers ----
    const int i   = tid & 63;
    const int grp = tid >> 6;                  // 0..3
    const int o   = o_tile * O_TILE + grp * 4;

    float c[4][NCOEF];
    const float* cp = &coef[((size_t)o * IN_DIM + i) * NCOEF];
    #pragma unroll
    for (int oo = 0; oo < 4; ++oo)
        #pragma unroll
        for (int t = 0; t < NCOEF; ++t)
            c[oo][t] = cp[(size_t)oo * IN_DIM * NCOEF + t];

    #pragma unroll
    for (int bb = 0; bb < B_TILE; ++bb) {
        const int p = bb * IN_DIM + i;
        const float4 v0 = *(const float4*)&lds[0 * PLANE + p * 4];
        const float4 v1 = *(const float4*)&lds[1 * PLANE + p * 4];
        const float4 v2 = *(const float4*)&lds[2 * PLANE + p * 4];

        float* op = &out[(size_t)(b0 + bb) * (OUT_DIM * IN_DIM) + o * IN_DIM + i];
        #pragma unroll
        for (int oo = 0; oo < 4; ++oo) {
            float acc;
            acc  = v0.x * c[oo][0] + v0.y * c[oo][1] + v0.z * c[oo][2] + v0.w * c[oo][3];
            acc += v1.x * c[oo][4] + v1.y * c[oo][5] + v1.z * c[oo][6] + v1.w * c[oo][7];
            acc += v2.x * c[oo][8] + v2.y * c[oo][9] + v2.z * c[oo][10];
            __builtin_nontemporal_store(acc, op + oo * IN_DIM);
        }
    }
}

extern "C" void kernel_launch(void* const* d_in, const int* in_sizes, int n_in,
                              void* d_out, int out_size, void* d_ws, size_t ws_size,
                              hipStream_t stream) {
    const float* x    = (const float*)d_in[0];
    const float* grid = (const float*)d_in[1];
    const float* coef = (const float*)d_in[2];
    float* out = (float*)d_out;

    const int nblocks = (BATCH / B_TILE) * (OUT_DIM / O_TILE);  // 2048
    kan_kernel<<<nblocks, 256, 0, stream>>>(x, grid, coef, out);
}

// Round 4
// 15.442 us; speedup vs baseline: 1.0713x; 1.0713x over previous
//
#include <hip/hip_runtime.h>

// KAN activation: out[b,o,i] = sum_t B_t(x[b,i]) * coef[o,i,t]
// B=2048, IN=OUT=64, uniform knots (15), order k=3, 11 basis funcs.
//
// Uniform grid -> closed-form cubic B-spline (4 nonzero weights, no division).
//
// Phase 0: stage block's coef tile (16 o x 64 i x 11 t = 45 KB, contiguous)
//          into LDS via coalesced float4 loads (11 per thread). This replaces
//          the former 44 uncoalesced scalar global loads per thread (44 B lane
//          stride -> ~44 x 64B segments per wave instr, the round-2 bottleneck).
// Phase 1: 2 (b,i) pairs per thread; analytic weights scattered into a dense
//          12-slot row stored as 3 float4 planes in LDS (conflict-free b128).
// Phase 2: thread owns (i, 4 consecutive o); 44 coef regs filled from LDS
//          (lane stride 11 words = odd -> conflict-free); 3x ds_read_b128
//          per batch row shared across 4 outputs; coalesced 256B stores.

#define BATCH    2048
#define IN_DIM   64
#define OUT_DIM  64
#define NCOEF    11     // G + k
#define B_TILE   8
#define O_TILE   16     // per block (4 groups x 4 o each)
#define NPAIR    (B_TILE * IN_DIM)        // 512
#define PLANE    (NPAIR * 4)              // floats per basis plane
#define CTILE    (O_TILE * IN_DIM * NCOEF) // 11264 floats

__global__ __launch_bounds__(256) void kan_kernel(
    const float* __restrict__ x,     // (2048, 64)
    const float* __restrict__ grid,  // (64, 64, 15) broadcast uniform knots
    const float* __restrict__ coef,  // (64, 64, 11)
    float* __restrict__ out)         // (2048, 64, 64)
{
    __shared__ float bas_lds[3 * PLANE];   // 24 KiB
    __shared__ float coef_lds[CTILE];      // 44 KiB (same flat layout as global)

    const int tid    = threadIdx.x;
    const int o_tile = blockIdx.x & 3;        // 4 o-tiles of 16
    const int b_tile = blockIdx.x >> 2;       // 256 b-tiles of 8
    const int b0     = b_tile * B_TILE;

    const float g0    = grid[0];
    const float inv_h = 1.0f / (grid[1] - g0);

    // ---- Phase 0: issue coalesced coef-tile loads (latency hides under
    //      phase 1), park in registers, write to LDS just before barrier ----
    const float4* csrc = (const float4*)(coef + (size_t)o_tile * O_TILE * IN_DIM * NCOEF);
    float4 cv[CTILE / 4 / 256];               // 11 float4 per thread
    #pragma unroll
    for (int q = 0; q < CTILE / 4 / 256; ++q)
        cv[q] = csrc[tid + q * 256];

    // ---- Phase 1: analytic cubic B-spline weights, 2 pairs per thread ----
    #pragma unroll
    for (int qq = 0; qq < NPAIR / 256; ++qq) {
        const int p  = tid + qq * 256;        // p = bb*64 + i
        const int bb = p >> 6;
        const int i  = p & 63;
        const float xv = x[(size_t)(b0 + bb) * IN_DIM + i];

        const float4 z = make_float4(0.f, 0.f, 0.f, 0.f);
        *(float4*)&bas_lds[0 * PLANE + p * 4] = z;
        *(float4*)&bas_lds[1 * PLANE + p * 4] = z;
        *(float4*)&bas_lds[2 * PLANE + p * 4] = z;

        const float pos = (xv - g0) * inv_h;   // cell position in [0,14)
        if (pos >= 0.0f && pos < 14.0f) {
            const int   m  = (int)pos;
            const float t  = pos - (float)m;
            const float t2 = t * t;
            const float t3 = t2 * t;
            const float s  = 1.0f - t;
            const float w0 = s * s * s * (1.0f / 6.0f);
            const float w1 = (3.0f * t3 - 6.0f * t2 + 4.0f) * (1.0f / 6.0f);
            const float w2 = (-3.0f * t3 + 3.0f * t2 + 3.0f * t + 1.0f) * (1.0f / 6.0f);
            const float w3 = t3 * (1.0f / 6.0f);

            const int mb = m - 3;              // dense index of w0
            int idx;
            idx = mb + 0; if ((unsigned)idx < NCOEF) bas_lds[(idx >> 2) * PLANE + p * 4 + (idx & 3)] = w0;
            idx = mb + 1; if ((unsigned)idx < NCOEF) bas_lds[(idx >> 2) * PLANE + p * 4 + (idx & 3)] = w1;
            idx = mb + 2; if ((unsigned)idx < NCOEF) bas_lds[(idx >> 2) * PLANE + p * 4 + (idx & 3)] = w2;
            idx = mb + 3; if ((unsigned)idx < NCOEF) bas_lds[(idx >> 2) * PLANE + p * 4 + (idx & 3)] = w3;
        }
    }

    // park coef tile in LDS (coalesced float4 writes, conflict-free)
    #pragma unroll
    for (int q = 0; q < CTILE / 4 / 256; ++q)
        *(float4*)&coef_lds[(tid + q * 256) * 4] = cv[q];

    __syncthreads();

    // ---- Phase 2: thread owns (i, 4 consecutive o); coef regs from LDS ----
    const int i   = tid & 63;
    const int grp = tid >> 6;                  // 0..3
    const int o   = o_tile * O_TILE + grp * 4;

    float c[4][NCOEF];
    #pragma unroll
    for (int oo = 0; oo < 4; ++oo) {
        const int row = ((grp * 4 + oo) * IN_DIM + i) * NCOEF;  // lane stride 11 -> conflict-free
        #pragma unroll
        for (int t = 0; t < NCOEF; ++t)
            c[oo][t] = coef_lds[row + t];
    }

    #pragma unroll
    for (int bb = 0; bb < B_TILE; ++bb) {
        const int p = bb * IN_DIM + i;
        const float4 v0 = *(const float4*)&bas_lds[0 * PLANE + p * 4];
        const float4 v1 = *(const float4*)&bas_lds[1 * PLANE + p * 4];
        const float4 v2 = *(const float4*)&bas_lds[2 * PLANE + p * 4];

        float* op = &out[(size_t)(b0 + bb) * (OUT_DIM * IN_DIM) + o * IN_DIM + i];
        #pragma unroll
        for (int oo = 0; oo < 4; ++oo) {
            float acc;
            acc  = v0.x * c[oo][0] + v0.y * c[oo][1] + v0.z * c[oo][2] + v0.w * c[oo][3];
            acc += v1.x * c[oo][4] + v1.y * c[oo][5] + v1.z * c[oo][6] + v1.w * c[oo][7];
            acc += v2.x * c[oo][8] + v2.y * c[oo][9] + v2.z * c[oo][10];
            op[oo * IN_DIM] = acc;
        }
    }
}

extern "C" void kernel_launch(void* const* d_in, const int* in_sizes, int n_in,
                              void* d_out, int out_size, void* d_ws, size_t ws_size,
                              hipStream_t stream) {
    const float* x    = (const float*)d_in[0];
    const float* grid = (const float*)d_in[1];
    const float* coef = (const float*)d_in[2];
    float* out = (float*)d_out;

    const int nblocks = (BATCH / B_TILE) * (OUT_DIM / O_TILE);  // 1024
    kan_kernel<<<nblocks, 256, 0, stream>>>(x, grid, coef, out);
}